// Round 26
// baseline (936.056 us; speedup 1.0000x reference)
//
#include <hip/hip_runtime.h>

#define N_NODES 100000
#define N_EDGES 200000
#define N_GRAPHS 4000
#define F_IN 44
#define HDIM 256
#define EDIM 512
#define NLAYERS 4

typedef float floatx4 __attribute__((ext_vector_type(4)));
typedef short bhalf8 __attribute__((ext_vector_type(8)));

__device__ __forceinline__ unsigned short f2bf(float f) {
    unsigned int u = __float_as_uint(f);
    u += 0x7FFFu + ((u >> 16) & 1u);          // RNE
    return (unsigned short)(u >> 16);
}
__device__ __forceinline__ float bf2f(unsigned short s) {
    return __uint_as_float(((unsigned int)s) << 16);
}

// async global->LDS, 16B/lane. ldst wave-uniform base; gsrc per-lane.
__device__ __forceinline__ void gload16(const void* gsrc, void* ldst) {
    __builtin_amdgcn_global_load_lds(
        (const __attribute__((address_space(1))) void*)gsrc,
        (__attribute__((address_space(3))) void*)ldst, 16, 0, 0);
}

// ---------------- zero fill ----------------
__global__ void zero_kernel(float* __restrict__ p, size_t n4) {
    size_t i = (size_t)blockIdx.x * blockDim.x + threadIdx.x;
    const size_t stride = (size_t)gridDim.x * blockDim.x;
    const float4 z = make_float4(0.f, 0.f, 0.f, 0.f);
    for (; i < n4; i += stride) ((float4*)p)[i] = z;
}

// ------- xprep: x fp32 [N][44] -> xb bf16 [N][64] zero-padded (coalesced 8B writes) -------
__global__ void xprep_kernel(const float* __restrict__ x, unsigned short* __restrict__ xb) {
    int idx = blockIdx.x * 256 + threadIdx.x;
    const int total = N_NODES * 16;               // 16 x ushort4 slots per node
    const int stride = gridDim.x * 256;
    for (; idx < total; idx += stride) {
        const int n = idx >> 4, k4 = idx & 15;
        ushort4 v = make_ushort4(0, 0, 0, 0);
        if (k4 < F_IN / 4) {                      // 11 valid float4 slots
            const float4 xv = *(const float4*)(x + (size_t)n * F_IN + k4 * 4);
            v.x = f2bf(xv.x); v.y = f2bf(xv.y); v.z = f2bf(xv.z); v.w = f2bf(xv.w);
        }
        *(ushort4*)(xb + (size_t)n * 64 + k4 * 4) = v;
    }
}

// ---------------- CSR build ----------------
__global__ void hist_kernel(const int* __restrict__ dst, int* __restrict__ deg) {
    const int e = blockIdx.x * 256 + threadIdx.x;
    if (e < N_EDGES) atomicAdd(&deg[dst[e]], 1);
}

__global__ void scan1_kernel(const int* __restrict__ deg, int* __restrict__ row_ptr,
                             int* __restrict__ blk) {
    __shared__ int s[256];
    const int i = blockIdx.x * 256 + threadIdx.x;
    s[threadIdx.x] = (i < N_NODES) ? deg[i] : 0;
    __syncthreads();
    for (int off = 1; off < 256; off <<= 1) {
        int t = (threadIdx.x >= off) ? s[threadIdx.x - off] : 0;
        __syncthreads();
        s[threadIdx.x] += t;
        __syncthreads();
    }
    if (i < N_NODES) row_ptr[i + 1] = s[threadIdx.x];
    if (threadIdx.x == 255) blk[blockIdx.x] = s[255];
}

__global__ void scan2_kernel(int* __restrict__ blk, int nb) {
    if (threadIdx.x == 0 && blockIdx.x == 0) {
        int run = 0;
        for (int b = 0; b < nb; ++b) { const int t = blk[b]; blk[b] = run; run += t; }
    }
}

__global__ void scan3_kernel(int* __restrict__ row_ptr, const int* __restrict__ blk) {
    const int i = blockIdx.x * 256 + threadIdx.x;
    if (i < N_NODES) row_ptr[i + 1] += blk[i >> 8];
    if (i == 0) row_ptr[0] = 0;
}

__global__ void cursor_kernel(const int* __restrict__ row_ptr, int* __restrict__ cursor) {
    const int i = blockIdx.x * 256 + threadIdx.x;
    if (i < N_NODES) cursor[i] = row_ptr[i];
}

__global__ void fill_kernel(const int* __restrict__ src, const int* __restrict__ dst,
                            int* __restrict__ cursor, int* __restrict__ eids) {
    const int e = blockIdx.x * 256 + threadIdx.x;
    if (e < N_EDGES) {
        const int pos = atomicAdd(&cursor[dst[e]], 1);
        eids[pos] = src[e];
    }
}

// ------- segment sort: deterministic eids order (replay-stable fp32 sums) -------
__global__ void sort_kernel(const int* __restrict__ row_ptr, int* __restrict__ eids) {
    const int n = blockIdx.x * 256 + threadIdx.x;
    if (n < N_NODES) {
        const int s = row_ptr[n], e = row_ptr[n + 1];
        for (int i = s + 1; i < e; ++i) {
            const int v = eids[i];
            int j = i - 1;
            while (j >= s && eids[j] > v) { eids[j + 1] = eids[j]; --j; }
            eids[j + 1] = v;
        }
    }
}

// ------- gather: z = h + sum_neigh h (bf16 h, fp32 acc); write bf16 [n][HDIM] -------
// r25: 32 lanes/node, 16B/lane (uint4 = 8 bf16). Two nodes per wave.
__global__ void gather_kernel(const unsigned short* __restrict__ h,
                              const int* __restrict__ row_ptr,
                              const int* __restrict__ eids, unsigned short* __restrict__ z) {
    const int tid = threadIdx.x;
    const int n = blockIdx.x * 8 + (tid >> 5);      // 8 nodes per 256-thr block
    const int t = tid & 31;                          // 16B granule within 512B row
    const uint4* h4 = (const uint4*)h;               // 8 bf16 per uint4
    const uint4 hv = h4[(size_t)n * 32 + t];
    float acc[8];
    acc[0] = bf2f((unsigned short)hv.x); acc[1] = bf2f((unsigned short)(hv.x >> 16));
    acc[2] = bf2f((unsigned short)hv.y); acc[3] = bf2f((unsigned short)(hv.y >> 16));
    acc[4] = bf2f((unsigned short)hv.z); acc[5] = bf2f((unsigned short)(hv.z >> 16));
    acc[6] = bf2f((unsigned short)hv.w); acc[7] = bf2f((unsigned short)(hv.w >> 16));
    const int s = row_ptr[n], e = row_ptr[n + 1];
    for (int i = s; i < e; ++i) {
        const uint4 v = h4[(size_t)eids[i] * 32 + t];
        acc[0] += bf2f((unsigned short)v.x); acc[1] += bf2f((unsigned short)(v.x >> 16));
        acc[2] += bf2f((unsigned short)v.y); acc[3] += bf2f((unsigned short)(v.y >> 16));
        acc[4] += bf2f((unsigned short)v.z); acc[5] += bf2f((unsigned short)(v.z >> 16));
        acc[6] += bf2f((unsigned short)v.w); acc[7] += bf2f((unsigned short)(v.w >> 16));
    }
    uint4 pk;
    pk.x = (unsigned int)f2bf(acc[0]) | ((unsigned int)f2bf(acc[1]) << 16);
    pk.y = (unsigned int)f2bf(acc[2]) | ((unsigned int)f2bf(acc[3]) << 16);
    pk.z = (unsigned int)f2bf(acc[4]) | ((unsigned int)f2bf(acc[5]) << 16);
    pk.w = (unsigned int)f2bf(acc[6]) | ((unsigned int)f2bf(acc[7]) << 16);
    ((uint4*)z)[(size_t)n * 32 + t] = pk;
}

// ------- fused weight prep: all weights -> transposed [N][K] bf16, one dispatch -------
__global__ void wprep_all(const float* __restrict__ W1, const float* __restrict__ W2,
                          const float* __restrict__ Wf1, const float* __restrict__ Wf2,
                          const float* __restrict__ Wa,
                          unsigned short* __restrict__ t1, unsigned short* __restrict__ t2,
                          unsigned short* __restrict__ tf1, unsigned short* __restrict__ tf2,
                          unsigned short* __restrict__ tat) {
    const int WSZ = HDIM * 2 * HDIM;                 // 131072
    const int T0 = 8 * WSZ;                          // W1+W2
    const int T1 = T0 + HDIM * HDIM;                 // +Wf1
    const int T2 = T1 + HDIM * EDIM;                 // +Wf2
    const int T3 = T2 + 64 * HDIM;                   // +W_atom (padded K=64)
    const int stride = gridDim.x * 256;
    for (int idx = blockIdx.x * 256 + threadIdx.x; idx < T3; idx += stride) {
        if (idx < 4 * WSZ) {                         // W1: K=256, N=512 -> t1 [512][256]
            const int l = idx >> 17, e = idx & (WSZ - 1);
            const int k = e >> 9, n = e & 511;
            t1[(size_t)l * WSZ + n * HDIM + k] = f2bf(W1[idx]);
        } else if (idx < T0) {                       // W2: K=512, N=256 -> t2 [256][512]
            const int r = idx - 4 * WSZ;
            const int l = r >> 17, e = r & (WSZ - 1);
            const int k = e >> 8, n = e & 255;
            t2[(size_t)l * WSZ + n * EDIM + k] = f2bf(W2[r]);
        } else if (idx < T1) {                       // Wf1 -> tf1 [256][256]
            const int e = idx - T0;
            const int k = e >> 8, n = e & 255;
            tf1[n * HDIM + k] = f2bf(Wf1[e]);
        } else if (idx < T2) {                       // Wf2: K=256, N=512 -> tf2 [512][256]
            const int e = idx - T1;
            const int k = e >> 9, n = e & 511;
            tf2[n * HDIM + k] = f2bf(Wf2[e]);
        } else {                                     // W_atom: [44][256] -> tat [256][64] pad0
            const int e = idx - T2;                  // e over 64*256, k-major per n
            const int n = e >> 6, k = e & 63;
            tat[n * 64 + k] = (k < F_IN) ? f2bf(Wa[k * HDIM + n]) : (unsigned short)0;
        }
    }
}

// ============ FUSED GIN LAYER (r26: 8 waves / 512 threads) ============
// H = relu(relu(zin@W1+b1)@W2+b2), z2 never leaves LDS. Same block tile (128x256),
// same LDS layout/barriers/K-order as r24 -> bit-identical output. Finer wave split:
//   phase A: wave (wr=w>>2, wc=w&3) owns z2c rows wr*64.., cols wc*16.. (acc_z[4])
//   phase B: wave owns H rows wr*64.., cols wc*64.. (acc_h[4][4], 64 VGPR vs 128)
// Per-wave unified regs ~halve -> waves/CU rises (was ~5, VGPR-capped); staging work
// per thread halves. sB2 early-issue (T14, r24) retained.
__global__ __launch_bounds__(512)
void fused_layer(const unsigned short* __restrict__ zin, const unsigned short* __restrict__ T1,
                 const unsigned short* __restrict__ T2, const float* __restrict__ b1,
                 const float* __restrict__ b2, unsigned short* __restrict__ H, int M) {
    // stageA 8192 | stageB1 4096 | zbuf 9216 ([128][72]) | stageB2 16384  = 37888 us (74KB)
    // epilogue aliases front 33792 us as [128][264]
    __shared__ __align__(16) unsigned short lds[37888];
    unsigned short* sA  = lds;
    unsigned short* sB1 = lds + 8192;
    unsigned short* zb  = lds + 12288;
    unsigned short* sB2 = lds + 21504;

    const int G = gridDim.x;
    int wg = blockIdx.x;
    {   // bijective XCD remap (m204)
        const int q = G >> 3, r = G & 7;
        const int xx = wg & 7, o = wg >> 3;
        wg = (xx < r ? xx * (q + 1) : r * (q + 1) + (xx - r) * q) + o;
    }
    const int row0 = wg << 7;

    const int tid = threadIdx.x;                            // 0..511
    const int lane = tid & 63;
    const int w = tid >> 6;                                 // 0..7
    const int wr = w >> 2, wc = w & 3;                      // 2 x 4 wave grid
    const int lr = lane & 15;
    const int l4 = lane >> 4;
    const int rgrp = l4 * 4;
    const int srow = tid >> 3;                              // 0..63
    const int sgran = ((tid & 7) ^ (srow & 7)) << 3;        // pre-swizzled src granule

    floatx4 acc_h[4][4];
#pragma unroll
    for (int m = 0; m < 4; ++m)
#pragma unroll
        for (int n = 0; n < 4; ++n) acc_h[m][n] = (floatx4){0.f, 0.f, 0.f, 0.f};

#pragma unroll 1
    for (int c = 0; c < 8; ++c) {
        floatx4 acc_z[4];
#pragma unroll
        for (int m = 0; m < 4; ++m) acc_z[m] = (floatx4){0.f, 0.f, 0.f, 0.f};

        // ---- phase A: 4 K-steps over zin K=256 ----
#pragma unroll 1
        for (int t = 0; t < 4; ++t) {
            __syncthreads();             // stage buffers free (t==0: prev sB2 readers too)
#pragma unroll
            for (int p = 0; p < 2; ++p) {                   // zin [128][64]: 2 passes x 64 rows
                const int r = (p << 6) + srow;
                int ar = row0 + r; if (ar >= M) ar = M - 1;
                gload16(zin + (size_t)ar * 256 + (t << 6) + sgran,
                        &sA[(p << 12) + (w << 9)]);
            }
            {                                               // W1 slice rows c*64.. [64][64]
                gload16(T1 + (size_t)((c << 6) + srow) * 256 + (t << 6) + sgran,
                        &sB1[(w << 9)]);
            }
            if (t == 0) {
                // early-issue W2T k-slice [256][64] for this c (T14)
#pragma unroll
                for (int p = 0; p < 4; ++p) {
                    const int r = (p << 6) + srow;
                    gload16(T2 + (size_t)r * 512 + (c << 6) + sgran,
                            &sB2[(p << 12) + (w << 9)]);
                }
            }
            __syncthreads();             // compiler drains vmcnt before barrier
#pragma unroll
            for (int s = 0; s < 2; ++s) {
                const int pg = (((s << 2) + l4) ^ (lr & 7)) << 3;
                bhalf8 fa[4], fb;
#pragma unroll
                for (int m = 0; m < 4; ++m)
                    fa[m] = *(const bhalf8*)&sA[((wr << 6) + (m << 4) + lr) * 64 + pg];
                fb = *(const bhalf8*)&sB1[((wc << 4) + lr) * 64 + pg];
#pragma unroll
                for (int m = 0; m < 4; ++m)
                    acc_z[m] = __builtin_amdgcn_mfma_f32_16x16x32_bf16(fa[m], fb, acc_z[m], 0, 0, 0);
            }
        }

        // ---- z2c -> zbuf (bf16, relu+bias), unswizzled [128][72] ----
        {
            const int ck = (wc << 4) + lr;                  // 0..63
            const float bv = b1[(c << 6) + ck];
#pragma unroll
            for (int m = 0; m < 4; ++m) {
                const int rw = (wr << 6) + (m << 4) + rgrp;
#pragma unroll
                for (int j = 0; j < 4; ++j)
                    zb[(rw + j) * 72 + ck] = f2bf(fmaxf(acc_z[m][j] + bv, 0.f));
            }
        }
        __syncthreads();                 // zbuf visible; sB2 landed long ago

        // ---- phase B: acc_h += zbuf[128][64] @ W2T-slice ----
#pragma unroll
        for (int s = 0; s < 2; ++s) {
            const int pg = (((s << 2) + l4) ^ (lr & 7)) << 3;
            const int zg = ((s << 2) + l4) << 3;            // zbuf granule (no swizzle)
            bhalf8 fa[4], fb[4];
#pragma unroll
            for (int m = 0; m < 4; ++m)
                fa[m] = *(const bhalf8*)&zb[((wr << 6) + (m << 4) + lr) * 72 + zg];
#pragma unroll
            for (int n = 0; n < 4; ++n)
                fb[n] = *(const bhalf8*)&sB2[((wc << 6) + (n << 4) + lr) * 64 + pg];
#pragma unroll
            for (int m = 0; m < 4; ++m)
#pragma unroll
                for (int n = 0; n < 4; ++n)
                    acc_h[m][n] = __builtin_amdgcn_mfma_f32_16x16x32_bf16(fa[m], fb[n], acc_h[m][n], 0, 0, 0);
        }
    }

    // ---- epilogue: relu+bias -> bf16, LDS-staged coalesced write (r12 pattern) ----
    __syncthreads();
#pragma unroll
    for (int n = 0; n < 4; ++n) {
        const int colt = (wc << 6) + (n << 4) + lr;
        const float bv = b2[colt];
#pragma unroll
        for (int m = 0; m < 4; ++m) {
            const int rwt = (wr << 6) + (m << 4) + rgrp;
#pragma unroll
            for (int j = 0; j < 4; ++j)
                lds[(rwt + j) * 264 + colt] = f2bf(fmaxf(acc_h[m][n][j] + bv, 0.f));
        }
    }
    __syncthreads();
    const int orow = tid >> 2;           // 0..127
    const int oq = (tid & 3) << 6;       // 0,64,128,192 ushorts (128B each)
    if (row0 + orow < M) {
        const uint4* sp = (const uint4*)(lds + orow * 264 + oq);
        uint4* dp = (uint4*)(H + (size_t)(row0 + orow) * 256 + oq);
#pragma unroll
        for (int q = 0; q < 8; ++q) dp[q] = sp[q];
    }
}

// ---------------- MFMA GEMM (r17): counted-vmcnt double-buffer; atom + head only ---------
template <int OUT>
__global__ __launch_bounds__(256)
void gemm_mfma(const unsigned short* __restrict__ A, const unsigned short* __restrict__ BT,
               const float* __restrict__ bias, float* __restrict__ C,
               unsigned short* __restrict__ Z, int M, int N, int KK) {
    __shared__ __align__(16) unsigned short lds_all[32768];   // 64 KB

    const int ncol = N >> 7;
    const int G = gridDim.x;
    int wg = blockIdx.x;
    {   // bijective XCD remap (m204)
        const int q = G >> 3, r = G & 7;
        const int xx = wg & 7, o = wg >> 3;
        wg = (xx < r ? xx * (q + 1) : r * (q + 1) + (xx - r) * q) + o;
    }
    const int col0 = (wg % ncol) << 7;
    const int row0 = (wg / ncol) << 7;

    const int tid = threadIdx.x;
    const int lane = tid & 63;
    const int w = tid >> 6;
    const int wr = w >> 1, wc = w & 1;
    const int lr = lane & 15;
    const int l4 = lane >> 4;
    const int srow = tid >> 3;
    const int sgran = ((tid & 7) ^ (srow & 7)) << 3;

    floatx4 acc[4][4];
#pragma unroll
    for (int m = 0; m < 4; ++m)
#pragma unroll
        for (int n = 0; n < 4; ++n) acc[m][n] = (floatx4){0.f, 0.f, 0.f, 0.f};

    const int NT = KK >> 6;

    auto stage = [&](int t, int b) {
        const int k0 = t << 6;
        unsigned short* la = &lds_all[b * 16384];
        unsigned short* lb = la + 8192;
#pragma unroll
        for (int pass = 0; pass < 4; ++pass) {
            const int r = (pass << 5) + srow;
            int ar = row0 + r; if (ar >= M) ar = M - 1;
            gload16(A + (size_t)ar * KK + k0 + sgran, &la[(pass << 11) + (w << 9)]);
            gload16(BT + (size_t)(col0 + r) * KK + k0 + sgran, &lb[(pass << 11) + (w << 9)]);
        }
    };

    stage(0, 0);
    if (NT > 1) stage(1, 1);
    for (int t = 0; t < NT; ++t) {
        const int cur = t & 1;
        if (t + 1 < NT) {
            asm volatile("s_waitcnt vmcnt(8)" ::: "memory");
        } else {
            asm volatile("s_waitcnt vmcnt(0)" ::: "memory");
        }
        __builtin_amdgcn_s_barrier();

        const unsigned short* la = &lds_all[cur * 16384];
        const unsigned short* lb = la + 8192;
#pragma unroll
        for (int s = 0; s < 2; ++s) {
            const int pg = (((s << 2) + l4) ^ (lr & 7)) << 3;
            bhalf8 fa[4], fb[4];
#pragma unroll
            for (int m = 0; m < 4; ++m)
                fa[m] = *(const bhalf8*)&la[((wr << 6) + (m << 4) + lr) * 64 + pg];
#pragma unroll
            for (int n = 0; n < 4; ++n)
                fb[n] = *(const bhalf8*)&lb[((wc << 6) + (n << 4) + lr) * 64 + pg];
#pragma unroll
            for (int m = 0; m < 4; ++m)
#pragma unroll
                for (int n = 0; n < 4; ++n)
                    acc[m][n] = __builtin_amdgcn_mfma_f32_16x16x32_bf16(fa[m], fb[n], acc[m][n], 0, 0, 0);
        }

        __builtin_amdgcn_s_barrier();
        if (t + 2 < NT) stage(t + 2, cur);
    }

    const int rgrp = l4 * 4;
    if (OUT == 2) {
        __syncthreads();
#pragma unroll
        for (int n = 0; n < 4; ++n) {
            const int colt = (wc << 6) + (n << 4) + lr;
            const float bv = bias[col0 + colt];
#pragma unroll
            for (int m = 0; m < 4; ++m) {
                const int rwt = (wr << 6) + (m << 4) + rgrp;
#pragma unroll
                for (int j = 0; j < 4; ++j)
                    lds_all[(rwt + j) * 136 + colt] = f2bf(fmaxf(acc[m][n][j] + bv, 0.f));
            }
        }
        __syncthreads();
        const int orow = tid >> 1;
        const int ocol = (tid & 1) << 6;
        if (row0 + orow < M) {
            const uint4* sp = (const uint4*)(lds_all + orow * 136 + ocol);
            uint4* dp = (uint4*)(Z + (size_t)(row0 + orow) * N + col0 + ocol);
#pragma unroll
            for (int q = 0; q < 8; ++q) dp[q] = sp[q];
        }
    } else {
#pragma unroll
        for (int n = 0; n < 4; ++n) {
            const int col = col0 + (wc << 6) + (n << 4) + lr;
            const float bv = bias[col];
#pragma unroll
            for (int m = 0; m < 4; ++m) {
                const int rw = row0 + (wr << 6) + (m << 4) + rgrp;
#pragma unroll
                for (int j = 0; j < 4; ++j) {
                    const int row = rw + j;
                    if (row < M) C[(size_t)row * N + col] = acc[m][n][j] + bv;
                }
            }
        }
    }
}

// ------- pool: sorted-batch segment mean over bf16 h -> bf16 [g][HDIM] -------
__global__ void pool_kernel(const unsigned short* __restrict__ h,
                            const int* __restrict__ batch,
                            unsigned short* __restrict__ gz) {
    __shared__ int sse[2];
    const int g = blockIdx.x;
    if (threadIdx.x < 2) {
        const int target = g + threadIdx.x;
        int lo = 0, hi = N_NODES;
        while (lo < hi) {
            const int mid = (lo + hi) >> 1;
            if (batch[mid] < target) lo = mid + 1; else hi = mid;
        }
        sse[threadIdx.x] = lo;
    }
    __syncthreads();
    const int s = sse[0], e = sse[1];
    const int j = threadIdx.x;
    float acc = 0.f;
    for (int n = s; n < e; ++n) acc += bf2f(h[(size_t)n * HDIM + j]);
    const float v = acc * ((e > s) ? 1.f / (float)(e - s) : 1.f);
    gz[(size_t)g * HDIM + j] = f2bf(v);
}

extern "C" void kernel_launch(void* const* d_in, const int* in_sizes, int n_in,
                              void* d_out, int out_size, void* d_ws, size_t ws_size,
                              hipStream_t stream) {
    const float* x      = (const float*)d_in[0];
    const int*   eidx   = (const int*)d_in[1];
    const int*   batch  = (const int*)d_in[2];
    const float* W_atom = (const float*)d_in[3];
    const float* b_atom = (const float*)d_in[4];
    const float* W1     = (const float*)d_in[5];
    const float* b1     = (const float*)d_in[6];
    const float* W2     = (const float*)d_in[7];
    const float* b2     = (const float*)d_in[8];
    const float* Wf1    = (const float*)d_in[9];
    const float* bf1    = (const float*)d_in[10];
    const float* Wf2    = (const float*)d_in[11];
    const float* bf2    = (const float*)d_in[12];
    float* out = (float*)d_out;

    const int* src = eidx;
    const int* dst = eidx + N_EDGES;

    const size_t NH = (size_t)N_NODES * HDIM;           // 25.6M elems
    const int WSZ = HDIM * 2 * HDIM;                    // 131072 elems per layer weight

    // ---- workspace layout ----
    char* base = (char*)d_ws;
    size_t off = 0;
    unsigned short* h = (unsigned short*)(base + off);      off += NH * 2;  // bf16 [N][256]
    unsigned short* zin = (unsigned short*)(base + off);    off += NH * 2;  // bf16 [N][256]
    unsigned short* xb = (unsigned short*)(base + off);     off += (size_t)N_NODES * 64 * 2;
    int* deg     = (int*)(base + off);            off += (size_t)N_NODES * 4;
    int* row_ptr = (int*)(base + off);            off += (size_t)(N_NODES + 1) * 4;
    int* cursor  = (int*)(base + off);            off += (size_t)N_NODES * 4;
    int* eids    = (int*)(base + off);            off += (size_t)N_EDGES * 4;
    int* blk     = (int*)(base + off);            off += 512 * 4;
    off = (off + 255) & ~(size_t)255;
    unsigned short* t1 = (unsigned short*)(base + off); off += (size_t)NLAYERS * WSZ * 2;
    unsigned short* t2 = (unsigned short*)(base + off); off += (size_t)NLAYERS * WSZ * 2;
    unsigned short* tf1 = (unsigned short*)(base + off); off += (size_t)HDIM * HDIM * 2;
    unsigned short* tf2 = (unsigned short*)(base + off); off += (size_t)HDIM * EDIM * 2;
    unsigned short* tat = (unsigned short*)(base + off); off += (size_t)HDIM * 64 * 2;
    off = (off + 255) & ~(size_t)255;

    // head buffers overlap the (dead-after-layers) zin region
    const size_t GH = (size_t)N_GRAPHS * HDIM;
    unsigned short* hg  = zin;            // [4000][256] bf16
    unsigned short* hg1 = zin + GH;       // [4000][256] bf16

    const int nb = (N_NODES + 255) / 256;
    const int nrow128 = (N_NODES + 127) / 128;   // 782

    // 1. x -> bf16 padded [N][64]; weights -> transposed bf16 (one dispatch each)
    xprep_kernel<<<1024, 256, 0, stream>>>(x, xb);
    wprep_all<<<1024, 256, 0, stream>>>(W1, W2, Wf1, Wf2, W_atom, t1, t2, tf1, tf2, tat);

    // 2. CSR build (+ deterministic segment sort)
    zero_kernel<<<128, 256, 0, stream>>>((float*)deg, N_NODES / 4);
    hist_kernel<<<(N_EDGES + 255) / 256, 256, 0, stream>>>(dst, deg);
    scan1_kernel<<<nb, 256, 0, stream>>>(deg, row_ptr, blk);
    scan2_kernel<<<1, 64, 0, stream>>>(blk, nb);
    scan3_kernel<<<nb, 256, 0, stream>>>(row_ptr, blk);
    cursor_kernel<<<nb, 256, 0, stream>>>(row_ptr, cursor);
    fill_kernel<<<(N_EDGES + 255) / 256, 256, 0, stream>>>(src, dst, cursor, eids);
    sort_kernel<<<nb, 256, 0, stream>>>(row_ptr, eids);   // deterministic gather order

    // 3. atom MLP as MFMA GEMM: h = relu(xb @ W_atom + b_atom)  [100000, 256], KK=64
    gemm_mfma<2><<<2 * nrow128, 256, 0, stream>>>(
        xb, tat, b_atom, nullptr, h, N_NODES, HDIM, 64);

    // 4. GIN layers: gather (8 nodes/block) + single fused kernel per layer (512 thr)
    for (int l = 0; l < NLAYERS; ++l) {
        gather_kernel<<<N_NODES / 8, 256, 0, stream>>>(h, row_ptr, eids, zin);
        fused_layer<<<nrow128, 512, 0, stream>>>(
            zin, t1 + (size_t)l * WSZ, t2 + (size_t)l * WSZ,
            b1 + (size_t)l * 2 * HDIM, b2 + (size_t)l * HDIM, h, N_NODES);
    }

    // 5. pool (bf16 in/out)
    pool_kernel<<<N_GRAPHS, HDIM, 0, stream>>>(h, batch, hg);

    // 6. head
    gemm_mfma<2><<<2 * ((N_GRAPHS + 127) / 128), 256, 0, stream>>>(
        hg, tf1, bf1, nullptr, hg1, N_GRAPHS, HDIM, HDIM);
    gemm_mfma<0><<<4 * ((N_GRAPHS + 127) / 128), 256, 0, stream>>>(
        hg1, tf2, bf2, out, nullptr, N_GRAPHS, EDIM, HDIM);
}

// Round 27
// 701.738 us; speedup vs baseline: 1.3339x; 1.3339x over previous
//
#include <hip/hip_runtime.h>

#define N_NODES 100000
#define N_EDGES 200000
#define N_GRAPHS 4000
#define F_IN 44
#define HDIM 256
#define EDIM 512
#define NLAYERS 4

typedef float floatx4 __attribute__((ext_vector_type(4)));
typedef short bhalf8 __attribute__((ext_vector_type(8)));

__device__ __forceinline__ unsigned short f2bf(float f) {
    unsigned int u = __float_as_uint(f);
    u += 0x7FFFu + ((u >> 16) & 1u);          // RNE
    return (unsigned short)(u >> 16);
}
__device__ __forceinline__ float bf2f(unsigned short s) {
    return __uint_as_float(((unsigned int)s) << 16);
}

// async global->LDS, 16B/lane. ldst wave-uniform base; gsrc per-lane.
__device__ __forceinline__ void gload16(const void* gsrc, void* ldst) {
    __builtin_amdgcn_global_load_lds(
        (const __attribute__((address_space(1))) void*)gsrc,
        (__attribute__((address_space(3))) void*)ldst, 16, 0, 0);
}

// ---------------- zero fill ----------------
__global__ void zero_kernel(float* __restrict__ p, size_t n4) {
    size_t i = (size_t)blockIdx.x * blockDim.x + threadIdx.x;
    const size_t stride = (size_t)gridDim.x * blockDim.x;
    const float4 z = make_float4(0.f, 0.f, 0.f, 0.f);
    for (; i < n4; i += stride) ((float4*)p)[i] = z;
}

// ------- xprep: x fp32 [N][44] -> xb bf16 [N][64] zero-padded (coalesced 8B writes) -------
__global__ void xprep_kernel(const float* __restrict__ x, unsigned short* __restrict__ xb) {
    int idx = blockIdx.x * 256 + threadIdx.x;
    const int total = N_NODES * 16;               // 16 x ushort4 slots per node
    const int stride = gridDim.x * 256;
    for (; idx < total; idx += stride) {
        const int n = idx >> 4, k4 = idx & 15;
        ushort4 v = make_ushort4(0, 0, 0, 0);
        if (k4 < F_IN / 4) {                      // 11 valid float4 slots
            const float4 xv = *(const float4*)(x + (size_t)n * F_IN + k4 * 4);
            v.x = f2bf(xv.x); v.y = f2bf(xv.y); v.z = f2bf(xv.z); v.w = f2bf(xv.w);
        }
        *(ushort4*)(xb + (size_t)n * 64 + k4 * 4) = v;
    }
}

// ---------------- CSR build ----------------
__global__ void hist_kernel(const int* __restrict__ dst, int* __restrict__ deg) {
    const int e = blockIdx.x * 256 + threadIdx.x;
    if (e < N_EDGES) atomicAdd(&deg[dst[e]], 1);
}

__global__ void scan1_kernel(const int* __restrict__ deg, int* __restrict__ row_ptr,
                             int* __restrict__ blk) {
    __shared__ int s[256];
    const int i = blockIdx.x * 256 + threadIdx.x;
    s[threadIdx.x] = (i < N_NODES) ? deg[i] : 0;
    __syncthreads();
    for (int off = 1; off < 256; off <<= 1) {
        int t = (threadIdx.x >= off) ? s[threadIdx.x - off] : 0;
        __syncthreads();
        s[threadIdx.x] += t;
        __syncthreads();
    }
    if (i < N_NODES) row_ptr[i + 1] = s[threadIdx.x];
    if (threadIdx.x == 255) blk[blockIdx.x] = s[255];
}

__global__ void scan2_kernel(int* __restrict__ blk, int nb) {
    if (threadIdx.x == 0 && blockIdx.x == 0) {
        int run = 0;
        for (int b = 0; b < nb; ++b) { const int t = blk[b]; blk[b] = run; run += t; }
    }
}

__global__ void scan3_kernel(int* __restrict__ row_ptr, const int* __restrict__ blk) {
    const int i = blockIdx.x * 256 + threadIdx.x;
    if (i < N_NODES) row_ptr[i + 1] += blk[i >> 8];
    if (i == 0) row_ptr[0] = 0;
}

__global__ void cursor_kernel(const int* __restrict__ row_ptr, int* __restrict__ cursor) {
    const int i = blockIdx.x * 256 + threadIdx.x;
    if (i < N_NODES) cursor[i] = row_ptr[i];
}

__global__ void fill_kernel(const int* __restrict__ src, const int* __restrict__ dst,
                            int* __restrict__ cursor, int* __restrict__ eids) {
    const int e = blockIdx.x * 256 + threadIdx.x;
    if (e < N_EDGES) {
        const int pos = atomicAdd(&cursor[dst[e]], 1);
        eids[pos] = src[e];
    }
}

// ------- segment sort: deterministic eids order (replay-stable fp32 sums) -------
__global__ void sort_kernel(const int* __restrict__ row_ptr, int* __restrict__ eids) {
    const int n = blockIdx.x * 256 + threadIdx.x;
    if (n < N_NODES) {
        const int s = row_ptr[n], e = row_ptr[n + 1];
        for (int i = s + 1; i < e; ++i) {
            const int v = eids[i];
            int j = i - 1;
            while (j >= s && eids[j] > v) { eids[j + 1] = eids[j]; --j; }
            eids[j + 1] = v;
        }
    }
}

// ------- gather: z = h + sum_neigh h (bf16 h, fp32 acc); write bf16 [n][HDIM] -------
// r25: 32 lanes/node, 16B/lane (uint4 = 8 bf16). Two nodes per wave -> two independent
// neighbor chains in flight; load count halves. Add order identical -> bit-identical.
__global__ void gather_kernel(const unsigned short* __restrict__ h,
                              const int* __restrict__ row_ptr,
                              const int* __restrict__ eids, unsigned short* __restrict__ z) {
    const int tid = threadIdx.x;
    const int n = blockIdx.x * 8 + (tid >> 5);      // 8 nodes per 256-thr block
    const int t = tid & 31;                          // 16B granule within 512B row
    const uint4* h4 = (const uint4*)h;               // 8 bf16 per uint4
    const uint4 hv = h4[(size_t)n * 32 + t];
    float acc[8];
    acc[0] = bf2f((unsigned short)hv.x); acc[1] = bf2f((unsigned short)(hv.x >> 16));
    acc[2] = bf2f((unsigned short)hv.y); acc[3] = bf2f((unsigned short)(hv.y >> 16));
    acc[4] = bf2f((unsigned short)hv.z); acc[5] = bf2f((unsigned short)(hv.z >> 16));
    acc[6] = bf2f((unsigned short)hv.w); acc[7] = bf2f((unsigned short)(hv.w >> 16));
    const int s = row_ptr[n], e = row_ptr[n + 1];
    for (int i = s; i < e; ++i) {
        const uint4 v = h4[(size_t)eids[i] * 32 + t];
        acc[0] += bf2f((unsigned short)v.x); acc[1] += bf2f((unsigned short)(v.x >> 16));
        acc[2] += bf2f((unsigned short)v.y); acc[3] += bf2f((unsigned short)(v.y >> 16));
        acc[4] += bf2f((unsigned short)v.z); acc[5] += bf2f((unsigned short)(v.z >> 16));
        acc[6] += bf2f((unsigned short)v.w); acc[7] += bf2f((unsigned short)(v.w >> 16));
    }
    uint4 pk;
    pk.x = (unsigned int)f2bf(acc[0]) | ((unsigned int)f2bf(acc[1]) << 16);
    pk.y = (unsigned int)f2bf(acc[2]) | ((unsigned int)f2bf(acc[3]) << 16);
    pk.z = (unsigned int)f2bf(acc[4]) | ((unsigned int)f2bf(acc[5]) << 16);
    pk.w = (unsigned int)f2bf(acc[6]) | ((unsigned int)f2bf(acc[7]) << 16);
    ((uint4*)z)[(size_t)n * 32 + t] = pk;
}

// ------- fused weight prep: all weights -> transposed [N][K] bf16, one dispatch -------
__global__ void wprep_all(const float* __restrict__ W1, const float* __restrict__ W2,
                          const float* __restrict__ Wf1, const float* __restrict__ Wf2,
                          const float* __restrict__ Wa,
                          unsigned short* __restrict__ t1, unsigned short* __restrict__ t2,
                          unsigned short* __restrict__ tf1, unsigned short* __restrict__ tf2,
                          unsigned short* __restrict__ tat) {
    const int WSZ = HDIM * 2 * HDIM;                 // 131072
    const int T0 = 8 * WSZ;                          // W1+W2
    const int T1 = T0 + HDIM * HDIM;                 // +Wf1
    const int T2 = T1 + HDIM * EDIM;                 // +Wf2
    const int T3 = T2 + 64 * HDIM;                   // +W_atom (padded K=64)
    const int stride = gridDim.x * 256;
    for (int idx = blockIdx.x * 256 + threadIdx.x; idx < T3; idx += stride) {
        if (idx < 4 * WSZ) {                         // W1: K=256, N=512 -> t1 [512][256]
            const int l = idx >> 17, e = idx & (WSZ - 1);
            const int k = e >> 9, n = e & 511;
            t1[(size_t)l * WSZ + n * HDIM + k] = f2bf(W1[idx]);
        } else if (idx < T0) {                       // W2: K=512, N=256 -> t2 [256][512]
            const int r = idx - 4 * WSZ;
            const int l = r >> 17, e = r & (WSZ - 1);
            const int k = e >> 8, n = e & 255;
            t2[(size_t)l * WSZ + n * EDIM + k] = f2bf(W2[r]);
        } else if (idx < T1) {                       // Wf1 -> tf1 [256][256]
            const int e = idx - T0;
            const int k = e >> 8, n = e & 255;
            tf1[n * HDIM + k] = f2bf(Wf1[e]);
        } else if (idx < T2) {                       // Wf2: K=256, N=512 -> tf2 [512][256]
            const int e = idx - T1;
            const int k = e >> 9, n = e & 511;
            tf2[n * HDIM + k] = f2bf(Wf2[e]);
        } else {                                     // W_atom: [44][256] -> tat [256][64] pad0
            const int e = idx - T2;                  // e over 64*256, k-major per n
            const int n = e >> 6, k = e & 63;
            tat[n * 64 + k] = (k < F_IN) ? f2bf(Wa[k * HDIM + n]) : (unsigned short)0;
        }
    }
}

// ============ FUSED GIN LAYER (r24/r25 verified best): 4 waves / 256 threads ============
// H = relu(relu(zin@W1+b1)@W2+b2), z2 never leaves LDS. sB2 early-issue at t==0 (T14).
// r26 lesson: 8-wave split raises bank conflicts (1.0M->1.8M) and barrier cost while
// LDS (74KB -> 2 blocks/CU) stays the occupancy cap — net -52%. Keep 4 waves.
__global__ __launch_bounds__(256, 2)
void fused_layer(const unsigned short* __restrict__ zin, const unsigned short* __restrict__ T1,
                 const unsigned short* __restrict__ T2, const float* __restrict__ b1,
                 const float* __restrict__ b2, unsigned short* __restrict__ H, int M) {
    // stageA 8192 | stageB1 4096 | zbuf 9216 ([128][72]) | stageB2 16384  = 37888 us (74KB)
    // epilogue aliases front 33792 us as [128][264]
    __shared__ __align__(16) unsigned short lds[37888];
    unsigned short* sA  = lds;
    unsigned short* sB1 = lds + 8192;
    unsigned short* zb  = lds + 12288;
    unsigned short* sB2 = lds + 21504;

    const int G = gridDim.x;
    int wg = blockIdx.x;
    {   // bijective XCD remap (m204)
        const int q = G >> 3, r = G & 7;
        const int xx = wg & 7, o = wg >> 3;
        wg = (xx < r ? xx * (q + 1) : r * (q + 1) + (xx - r) * q) + o;
    }
    const int row0 = wg << 7;

    const int tid = threadIdx.x;
    const int lane = tid & 63;
    const int w = tid >> 6;
    const int wr = w >> 1, wc = w & 1;
    const int lr = lane & 15;
    const int l4 = lane >> 4;
    const int rgrp = l4 * 4;
    const int srow = tid >> 3;                              // 0..31
    const int sgran = ((tid & 7) ^ (srow & 7)) << 3;        // pre-swizzled src granule

    floatx4 acc_h[4][8];
#pragma unroll
    for (int m = 0; m < 4; ++m)
#pragma unroll
        for (int n = 0; n < 8; ++n) acc_h[m][n] = (floatx4){0.f, 0.f, 0.f, 0.f};

#pragma unroll 1
    for (int c = 0; c < 8; ++c) {
        floatx4 acc_z[4][2];
#pragma unroll
        for (int m = 0; m < 4; ++m)
#pragma unroll
            for (int n = 0; n < 2; ++n) acc_z[m][n] = (floatx4){0.f, 0.f, 0.f, 0.f};

        // ---- phase A: 4 K-steps over zin K=256 ----
#pragma unroll 1
        for (int t = 0; t < 4; ++t) {
            __syncthreads();             // stage buffers free (t==0: prev sB2 readers too)
#pragma unroll
            for (int p = 0; p < 4; ++p) {                   // zin [128][64]
                const int r = (p << 5) + srow;
                int ar = row0 + r; if (ar >= M) ar = M - 1;
                gload16(zin + (size_t)ar * 256 + (t << 6) + sgran, &sA[(p << 11) + (w << 9)]);
            }
#pragma unroll
            for (int p = 0; p < 2; ++p) {                   // W1 slice rows c*64.. [64][64]
                const int r = (p << 5) + srow;
                gload16(T1 + (size_t)((c << 6) + r) * 256 + (t << 6) + sgran,
                        &sB1[(p << 11) + (w << 9)]);
            }
            if (t == 0) {
                // early-issue W2T k-slice [256][64] for this c (T14): latency hides
                // under the whole of phase A instead of the zbuf-write window.
#pragma unroll
                for (int p = 0; p < 8; ++p) {
                    const int r = (p << 5) + srow;
                    gload16(T2 + (size_t)r * 512 + (c << 6) + sgran,
                            &sB2[(p << 11) + (w << 9)]);
                }
            }
            __syncthreads();             // compiler drains vmcnt before barrier
#pragma unroll
            for (int s = 0; s < 2; ++s) {
                const int pg = (((s << 2) + l4) ^ (lr & 7)) << 3;
                bhalf8 fa[4], fb[2];
#pragma unroll
                for (int m = 0; m < 4; ++m)
                    fa[m] = *(const bhalf8*)&sA[((wr << 6) + (m << 4) + lr) * 64 + pg];
#pragma unroll
                for (int n = 0; n < 2; ++n)
                    fb[n] = *(const bhalf8*)&sB1[((wc << 5) + (n << 4) + lr) * 64 + pg];
#pragma unroll
                for (int m = 0; m < 4; ++m)
#pragma unroll
                    for (int n = 0; n < 2; ++n)
                        acc_z[m][n] = __builtin_amdgcn_mfma_f32_16x16x32_bf16(fa[m], fb[n], acc_z[m][n], 0, 0, 0);
            }
        }

        // ---- z2c -> zbuf (bf16, relu+bias), unswizzled [128][72] ----
#pragma unroll
        for (int n = 0; n < 2; ++n) {
            const int ck = (wc << 5) + (n << 4) + lr;       // 0..63
            const float bv = b1[(c << 6) + ck];
#pragma unroll
            for (int m = 0; m < 4; ++m) {
                const int rw = (wr << 6) + (m << 4) + rgrp;
#pragma unroll
                for (int j = 0; j < 4; ++j)
                    zb[(rw + j) * 72 + ck] = f2bf(fmaxf(acc_z[m][n][j] + bv, 0.f));
            }
        }
        __syncthreads();                 // zbuf visible; sB2 landed long ago

        // ---- phase B: acc_h += zbuf[128][64] @ W2T-slice ----
#pragma unroll
        for (int s = 0; s < 2; ++s) {
            const int pg = (((s << 2) + l4) ^ (lr & 7)) << 3;
            const int zg = ((s << 2) + l4) << 3;            // zbuf granule (no swizzle)
            bhalf8 fa[4], fb[8];
#pragma unroll
            for (int m = 0; m < 4; ++m)
                fa[m] = *(const bhalf8*)&zb[((wr << 6) + (m << 4) + lr) * 72 + zg];
#pragma unroll
            for (int n = 0; n < 8; ++n)
                fb[n] = *(const bhalf8*)&sB2[((wc << 7) + (n << 4) + lr) * 64 + pg];
#pragma unroll
            for (int m = 0; m < 4; ++m)
#pragma unroll
                for (int n = 0; n < 8; ++n)
                    acc_h[m][n] = __builtin_amdgcn_mfma_f32_16x16x32_bf16(fa[m], fb[n], acc_h[m][n], 0, 0, 0);
        }
    }

    // ---- epilogue: relu+bias -> bf16, LDS-staged coalesced write (r12 pattern) ----
    __syncthreads();
#pragma unroll
    for (int n = 0; n < 8; ++n) {
        const int colt = (wc << 7) + (n << 4) + lr;
        const float bv = b2[colt];
#pragma unroll
        for (int m = 0; m < 4; ++m) {
            const int rwt = (wr << 6) + (m << 4) + rgrp;
#pragma unroll
            for (int j = 0; j < 4; ++j)
                lds[(rwt + j) * 264 + colt] = f2bf(fmaxf(acc_h[m][n][j] + bv, 0.f));
        }
    }
    __syncthreads();
    const int orow = tid >> 1;
    const int ohalf = (tid & 1) << 7;    // 128 us = 256B halves
    if (row0 + orow < M) {
        const uint4* sp = (const uint4*)(lds + orow * 264 + ohalf);
        uint4* dp = (uint4*)(H + (size_t)(row0 + orow) * 256 + ohalf);
#pragma unroll
        for (int q = 0; q < 16; ++q) dp[q] = sp[q];
    }
}

// ---------------- MFMA GEMM (r17): counted-vmcnt double-buffer; atom + head only ---------
template <int OUT>
__global__ __launch_bounds__(256)
void gemm_mfma(const unsigned short* __restrict__ A, const unsigned short* __restrict__ BT,
               const float* __restrict__ bias, float* __restrict__ C,
               unsigned short* __restrict__ Z, int M, int N, int KK) {
    __shared__ __align__(16) unsigned short lds_all[32768];   // 64 KB

    const int ncol = N >> 7;
    const int G = gridDim.x;
    int wg = blockIdx.x;
    {   // bijective XCD remap (m204)
        const int q = G >> 3, r = G & 7;
        const int xx = wg & 7, o = wg >> 3;
        wg = (xx < r ? xx * (q + 1) : r * (q + 1) + (xx - r) * q) + o;
    }
    const int col0 = (wg % ncol) << 7;
    const int row0 = (wg / ncol) << 7;

    const int tid = threadIdx.x;
    const int lane = tid & 63;
    const int w = tid >> 6;
    const int wr = w >> 1, wc = w & 1;
    const int lr = lane & 15;
    const int l4 = lane >> 4;
    const int srow = tid >> 3;
    const int sgran = ((tid & 7) ^ (srow & 7)) << 3;

    floatx4 acc[4][4];
#pragma unroll
    for (int m = 0; m < 4; ++m)
#pragma unroll
        for (int n = 0; n < 4; ++n) acc[m][n] = (floatx4){0.f, 0.f, 0.f, 0.f};

    const int NT = KK >> 6;

    auto stage = [&](int t, int b) {
        const int k0 = t << 6;
        unsigned short* la = &lds_all[b * 16384];
        unsigned short* lb = la + 8192;
#pragma unroll
        for (int pass = 0; pass < 4; ++pass) {
            const int r = (pass << 5) + srow;
            int ar = row0 + r; if (ar >= M) ar = M - 1;
            gload16(A + (size_t)ar * KK + k0 + sgran, &la[(pass << 11) + (w << 9)]);
            gload16(BT + (size_t)(col0 + r) * KK + k0 + sgran, &lb[(pass << 11) + (w << 9)]);
        }
    };

    stage(0, 0);
    if (NT > 1) stage(1, 1);
    for (int t = 0; t < NT; ++t) {
        const int cur = t & 1;
        if (t + 1 < NT) {
            asm volatile("s_waitcnt vmcnt(8)" ::: "memory");
        } else {
            asm volatile("s_waitcnt vmcnt(0)" ::: "memory");
        }
        __builtin_amdgcn_s_barrier();

        const unsigned short* la = &lds_all[cur * 16384];
        const unsigned short* lb = la + 8192;
#pragma unroll
        for (int s = 0; s < 2; ++s) {
            const int pg = (((s << 2) + l4) ^ (lr & 7)) << 3;
            bhalf8 fa[4], fb[4];
#pragma unroll
            for (int m = 0; m < 4; ++m)
                fa[m] = *(const bhalf8*)&la[((wr << 6) + (m << 4) + lr) * 64 + pg];
#pragma unroll
            for (int n = 0; n < 4; ++n)
                fb[n] = *(const bhalf8*)&lb[((wc << 6) + (n << 4) + lr) * 64 + pg];
#pragma unroll
            for (int m = 0; m < 4; ++m)
#pragma unroll
                for (int n = 0; n < 4; ++n)
                    acc[m][n] = __builtin_amdgcn_mfma_f32_16x16x32_bf16(fa[m], fb[n], acc[m][n], 0, 0, 0);
        }

        __builtin_amdgcn_s_barrier();
        if (t + 2 < NT) stage(t + 2, cur);
    }

    const int rgrp = l4 * 4;
    if (OUT == 2) {
        __syncthreads();
#pragma unroll
        for (int n = 0; n < 4; ++n) {
            const int colt = (wc << 6) + (n << 4) + lr;
            const float bv = bias[col0 + colt];
#pragma unroll
            for (int m = 0; m < 4; ++m) {
                const int rwt = (wr << 6) + (m << 4) + rgrp;
#pragma unroll
                for (int j = 0; j < 4; ++j)
                    lds_all[(rwt + j) * 136 + colt] = f2bf(fmaxf(acc[m][n][j] + bv, 0.f));
            }
        }
        __syncthreads();
        const int orow = tid >> 1;
        const int ocol = (tid & 1) << 6;
        if (row0 + orow < M) {
            const uint4* sp = (const uint4*)(lds_all + orow * 136 + ocol);
            uint4* dp = (uint4*)(Z + (size_t)(row0 + orow) * N + col0 + ocol);
#pragma unroll
            for (int q = 0; q < 8; ++q) dp[q] = sp[q];
        }
    } else {
#pragma unroll
        for (int n = 0; n < 4; ++n) {
            const int col = col0 + (wc << 6) + (n << 4) + lr;
            const float bv = bias[col];
#pragma unroll
            for (int m = 0; m < 4; ++m) {
                const int rw = row0 + (wr << 6) + (m << 4) + rgrp;
#pragma unroll
                for (int j = 0; j < 4; ++j) {
                    const int row = rw + j;
                    if (row < M) C[(size_t)row * N + col] = acc[m][n][j] + bv;
                }
            }
        }
    }
}

// ------- pool: sorted-batch segment mean over bf16 h -> bf16 [g][HDIM] -------
__global__ void pool_kernel(const unsigned short* __restrict__ h,
                            const int* __restrict__ batch,
                            unsigned short* __restrict__ gz) {
    __shared__ int sse[2];
    const int g = blockIdx.x;
    if (threadIdx.x < 2) {
        const int target = g + threadIdx.x;
        int lo = 0, hi = N_NODES;
        while (lo < hi) {
            const int mid = (lo + hi) >> 1;
            if (batch[mid] < target) lo = mid + 1; else hi = mid;
        }
        sse[threadIdx.x] = lo;
    }
    __syncthreads();
    const int s = sse[0], e = sse[1];
    const int j = threadIdx.x;
    float acc = 0.f;
    for (int n = s; n < e; ++n) acc += bf2f(h[(size_t)n * HDIM + j]);
    const float v = acc * ((e > s) ? 1.f / (float)(e - s) : 1.f);
    gz[(size_t)g * HDIM + j] = f2bf(v);
}

extern "C" void kernel_launch(void* const* d_in, const int* in_sizes, int n_in,
                              void* d_out, int out_size, void* d_ws, size_t ws_size,
                              hipStream_t stream) {
    const float* x      = (const float*)d_in[0];
    const int*   eidx   = (const int*)d_in[1];
    const int*   batch  = (const int*)d_in[2];
    const float* W_atom = (const float*)d_in[3];
    const float* b_atom = (const float*)d_in[4];
    const float* W1     = (const float*)d_in[5];
    const float* b1     = (const float*)d_in[6];
    const float* W2     = (const float*)d_in[7];
    const float* b2     = (const float*)d_in[8];
    const float* Wf1    = (const float*)d_in[9];
    const float* bf1    = (const float*)d_in[10];
    const float* Wf2    = (const float*)d_in[11];
    const float* bf2    = (const float*)d_in[12];
    float* out = (float*)d_out;

    const int* src = eidx;
    const int* dst = eidx + N_EDGES;

    const size_t NH = (size_t)N_NODES * HDIM;           // 25.6M elems
    const int WSZ = HDIM * 2 * HDIM;                    // 131072 elems per layer weight

    // ---- workspace layout ----
    char* base = (char*)d_ws;
    size_t off = 0;
    unsigned short* h = (unsigned short*)(base + off);      off += NH * 2;  // bf16 [N][256]
    unsigned short* zin = (unsigned short*)(base + off);    off += NH * 2;  // bf16 [N][256]
    unsigned short* xb = (unsigned short*)(base + off);     off += (size_t)N_NODES * 64 * 2;
    int* deg     = (int*)(base + off);            off += (size_t)N_NODES * 4;
    int* row_ptr = (int*)(base + off);            off += (size_t)(N_NODES + 1) * 4;
    int* cursor  = (int*)(base + off);            off += (size_t)N_NODES * 4;
    int* eids    = (int*)(base + off);            off += (size_t)N_EDGES * 4;
    int* blk     = (int*)(base + off);            off += 512 * 4;
    off = (off + 255) & ~(size_t)255;
    unsigned short* t1 = (unsigned short*)(base + off); off += (size_t)NLAYERS * WSZ * 2;
    unsigned short* t2 = (unsigned short*)(base + off); off += (size_t)NLAYERS * WSZ * 2;
    unsigned short* tf1 = (unsigned short*)(base + off); off += (size_t)HDIM * HDIM * 2;
    unsigned short* tf2 = (unsigned short*)(base + off); off += (size_t)HDIM * EDIM * 2;
    unsigned short* tat = (unsigned short*)(base + off); off += (size_t)HDIM * 64 * 2;
    off = (off + 255) & ~(size_t)255;

    // head buffers overlap the (dead-after-layers) zin region
    const size_t GH = (size_t)N_GRAPHS * HDIM;
    unsigned short* hg  = zin;            // [4000][256] bf16
    unsigned short* hg1 = zin + GH;       // [4000][256] bf16

    const int nb = (N_NODES + 255) / 256;
    const int nrow128 = (N_NODES + 127) / 128;   // 782

    // 1. x -> bf16 padded [N][64]; weights -> transposed bf16 (one dispatch each)
    xprep_kernel<<<1024, 256, 0, stream>>>(x, xb);
    wprep_all<<<1024, 256, 0, stream>>>(W1, W2, Wf1, Wf2, W_atom, t1, t2, tf1, tf2, tat);

    // 2. CSR build (+ deterministic segment sort)
    zero_kernel<<<128, 256, 0, stream>>>((float*)deg, N_NODES / 4);
    hist_kernel<<<(N_EDGES + 255) / 256, 256, 0, stream>>>(dst, deg);
    scan1_kernel<<<nb, 256, 0, stream>>>(deg, row_ptr, blk);
    scan2_kernel<<<1, 64, 0, stream>>>(blk, nb);
    scan3_kernel<<<nb, 256, 0, stream>>>(row_ptr, blk);
    cursor_kernel<<<nb, 256, 0, stream>>>(row_ptr, cursor);
    fill_kernel<<<(N_EDGES + 255) / 256, 256, 0, stream>>>(src, dst, cursor, eids);
    sort_kernel<<<nb, 256, 0, stream>>>(row_ptr, eids);   // deterministic gather order

    // 3. atom MLP as MFMA GEMM: h = relu(xb @ W_atom + b_atom)  [100000, 256], KK=64
    gemm_mfma<2><<<2 * nrow128, 256, 0, stream>>>(
        xb, tat, b_atom, nullptr, h, N_NODES, HDIM, 64);

    // 4. GIN layers: gather (8 nodes/block) + single fused kernel per layer
    for (int l = 0; l < NLAYERS; ++l) {
        gather_kernel<<<N_NODES / 8, 256, 0, stream>>>(h, row_ptr, eids, zin);
        fused_layer<<<nrow128, 256, 0, stream>>>(
            zin, t1 + (size_t)l * WSZ, t2 + (size_t)l * WSZ,
            b1 + (size_t)l * 2 * HDIM, b2 + (size_t)l * HDIM, h, N_NODES);
    }

    // 5. pool (bf16 in/out)
    pool_kernel<<<N_GRAPHS, HDIM, 0, stream>>>(h, batch, hg);

    // 6. head
    gemm_mfma<2><<<2 * ((N_GRAPHS + 127) / 128), 256, 0, stream>>>(
        hg, tf1, bf1, nullptr, hg1, N_GRAPHS, HDIM, HDIM);
    gemm_mfma<0><<<4 * ((N_GRAPHS + 127) / 128), 256, 0, stream>>>(
        hg1, tf2, bf2, out, nullptr, N_GRAPHS, EDIM, HDIM);
}

// Round 28
// 692.675 us; speedup vs baseline: 1.3514x; 1.0131x over previous
//
#include <hip/hip_runtime.h>

#define N_NODES 100000
#define N_EDGES 200000
#define N_GRAPHS 4000
#define F_IN 44
#define HDIM 256
#define EDIM 512
#define NLAYERS 4

typedef float floatx4 __attribute__((ext_vector_type(4)));
typedef short bhalf8 __attribute__((ext_vector_type(8)));

__device__ __forceinline__ unsigned short f2bf(float f) {
    unsigned int u = __float_as_uint(f);
    u += 0x7FFFu + ((u >> 16) & 1u);          // RNE
    return (unsigned short)(u >> 16);
}
__device__ __forceinline__ float bf2f(unsigned short s) {
    return __uint_as_float(((unsigned int)s) << 16);
}

// async global->LDS, 16B/lane. ldst wave-uniform base; gsrc per-lane.
__device__ __forceinline__ void gload16(const void* gsrc, void* ldst) {
    __builtin_amdgcn_global_load_lds(
        (const __attribute__((address_space(1))) void*)gsrc,
        (__attribute__((address_space(3))) void*)ldst, 16, 0, 0);
}

// ---------------- zero fill ----------------
__global__ void zero_kernel(float* __restrict__ p, size_t n4) {
    size_t i = (size_t)blockIdx.x * blockDim.x + threadIdx.x;
    const size_t stride = (size_t)gridDim.x * blockDim.x;
    const float4 z = make_float4(0.f, 0.f, 0.f, 0.f);
    for (; i < n4; i += stride) ((float4*)p)[i] = z;
}

// ---------------- CSR build ----------------
__global__ void hist_kernel(const int* __restrict__ dst, int* __restrict__ deg) {
    const int e = blockIdx.x * 256 + threadIdx.x;
    if (e < N_EDGES) atomicAdd(&deg[dst[e]], 1);
}

__global__ void scan1_kernel(const int* __restrict__ deg, int* __restrict__ row_ptr,
                             int* __restrict__ blk) {
    __shared__ int s[256];
    const int i = blockIdx.x * 256 + threadIdx.x;
    s[threadIdx.x] = (i < N_NODES) ? deg[i] : 0;
    __syncthreads();
    for (int off = 1; off < 256; off <<= 1) {
        int t = (threadIdx.x >= off) ? s[threadIdx.x - off] : 0;
        __syncthreads();
        s[threadIdx.x] += t;
        __syncthreads();
    }
    if (i < N_NODES) row_ptr[i + 1] = s[threadIdx.x];
    if (threadIdx.x == 255) blk[blockIdx.x] = s[255];
}

__global__ void scan2_kernel(int* __restrict__ blk, int nb) {
    if (threadIdx.x == 0 && blockIdx.x == 0) {
        int run = 0;
        for (int b = 0; b < nb; ++b) { const int t = blk[b]; blk[b] = run; run += t; }
    }
}

// r28: scan3 also writes cursor (saves a launch). Thread i computes the FINAL
// row_ptr[i+1] and writes it to both row_ptr[i+1] and cursor[i+1] (single writer
// per location -> race-free); i==0 thread writes row_ptr[0]=cursor[0]=0.
__global__ void scan3_kernel(int* __restrict__ row_ptr, const int* __restrict__ blk,
                             int* __restrict__ cursor) {
    const int i = blockIdx.x * 256 + threadIdx.x;
    if (i < N_NODES) {
        const int v = row_ptr[i + 1] + blk[i >> 8];
        row_ptr[i + 1] = v;
        if (i + 1 < N_NODES) cursor[i + 1] = v;
    }
    if (i == 0) { row_ptr[0] = 0; cursor[0] = 0; }
}

__global__ void fill_kernel(const int* __restrict__ src, const int* __restrict__ dst,
                            int* __restrict__ cursor, int* __restrict__ eids) {
    const int e = blockIdx.x * 256 + threadIdx.x;
    if (e < N_EDGES) {
        const int pos = atomicAdd(&cursor[dst[e]], 1);
        eids[pos] = src[e];
    }
}

// ------- segment sort: deterministic eids order (replay-stable fp32 sums) -------
__global__ void sort_kernel(const int* __restrict__ row_ptr, int* __restrict__ eids) {
    const int n = blockIdx.x * 256 + threadIdx.x;
    if (n < N_NODES) {
        const int s = row_ptr[n], e = row_ptr[n + 1];
        for (int i = s + 1; i < e; ++i) {
            const int v = eids[i];
            int j = i - 1;
            while (j >= s && eids[j] > v) { eids[j + 1] = eids[j]; --j; }
            eids[j + 1] = v;
        }
    }
}

// ------- gather: z = h + sum_neigh h (bf16 h, fp32 acc); write bf16 [n][HDIM] -------
// r25: 32 lanes/node, 16B/lane (uint4 = 8 bf16); two nodes per wave.
// r28: neighbor loop 2-way unrolled — both uint4 loads issued before the adds
// (2x memory-level parallelism within a chain). Per-element add order preserved
// exactly (v_i before v_{i+1}, k ascending) -> bit-identical, deterministic.
__global__ void gather_kernel(const unsigned short* __restrict__ h,
                              const int* __restrict__ row_ptr,
                              const int* __restrict__ eids, unsigned short* __restrict__ z) {
    const int tid = threadIdx.x;
    const int n = blockIdx.x * 8 + (tid >> 5);      // 8 nodes per 256-thr block
    const int t = tid & 31;                          // 16B granule within 512B row
    const uint4* h4 = (const uint4*)h;               // 8 bf16 per uint4
    const uint4 hv = h4[(size_t)n * 32 + t];
    float acc[8];
    acc[0] = bf2f((unsigned short)hv.x); acc[1] = bf2f((unsigned short)(hv.x >> 16));
    acc[2] = bf2f((unsigned short)hv.y); acc[3] = bf2f((unsigned short)(hv.y >> 16));
    acc[4] = bf2f((unsigned short)hv.z); acc[5] = bf2f((unsigned short)(hv.z >> 16));
    acc[6] = bf2f((unsigned short)hv.w); acc[7] = bf2f((unsigned short)(hv.w >> 16));
    const int s = row_ptr[n], e = row_ptr[n + 1];
    int i = s;
    for (; i + 1 < e; i += 2) {
        const uint4 v0 = h4[(size_t)eids[i] * 32 + t];
        const uint4 v1 = h4[(size_t)eids[i + 1] * 32 + t];
        acc[0] += bf2f((unsigned short)v0.x); acc[1] += bf2f((unsigned short)(v0.x >> 16));
        acc[2] += bf2f((unsigned short)v0.y); acc[3] += bf2f((unsigned short)(v0.y >> 16));
        acc[4] += bf2f((unsigned short)v0.z); acc[5] += bf2f((unsigned short)(v0.z >> 16));
        acc[6] += bf2f((unsigned short)v0.w); acc[7] += bf2f((unsigned short)(v0.w >> 16));
        acc[0] += bf2f((unsigned short)v1.x); acc[1] += bf2f((unsigned short)(v1.x >> 16));
        acc[2] += bf2f((unsigned short)v1.y); acc[3] += bf2f((unsigned short)(v1.y >> 16));
        acc[4] += bf2f((unsigned short)v1.z); acc[5] += bf2f((unsigned short)(v1.z >> 16));
        acc[6] += bf2f((unsigned short)v1.w); acc[7] += bf2f((unsigned short)(v1.w >> 16));
    }
    if (i < e) {
        const uint4 v = h4[(size_t)eids[i] * 32 + t];
        acc[0] += bf2f((unsigned short)v.x); acc[1] += bf2f((unsigned short)(v.x >> 16));
        acc[2] += bf2f((unsigned short)v.y); acc[3] += bf2f((unsigned short)(v.y >> 16));
        acc[4] += bf2f((unsigned short)v.z); acc[5] += bf2f((unsigned short)(v.z >> 16));
        acc[6] += bf2f((unsigned short)v.w); acc[7] += bf2f((unsigned short)(v.w >> 16));
    }
    uint4 pk;
    pk.x = (unsigned int)f2bf(acc[0]) | ((unsigned int)f2bf(acc[1]) << 16);
    pk.y = (unsigned int)f2bf(acc[2]) | ((unsigned int)f2bf(acc[3]) << 16);
    pk.z = (unsigned int)f2bf(acc[4]) | ((unsigned int)f2bf(acc[5]) << 16);
    pk.w = (unsigned int)f2bf(acc[6]) | ((unsigned int)f2bf(acc[7]) << 16);
    ((uint4*)z)[(size_t)n * 32 + t] = pk;
}

// ------- fused prep: all weights -> transposed [N][K] bf16, AND x -> xb (one dispatch) ----
__global__ void wprep_all(const float* __restrict__ W1, const float* __restrict__ W2,
                          const float* __restrict__ Wf1, const float* __restrict__ Wf2,
                          const float* __restrict__ Wa, const float* __restrict__ x,
                          unsigned short* __restrict__ t1, unsigned short* __restrict__ t2,
                          unsigned short* __restrict__ tf1, unsigned short* __restrict__ tf2,
                          unsigned short* __restrict__ tat, unsigned short* __restrict__ xb) {
    const int WSZ = HDIM * 2 * HDIM;                 // 131072
    const int T0 = 8 * WSZ;                          // W1+W2
    const int T1 = T0 + HDIM * HDIM;                 // +Wf1
    const int T2 = T1 + HDIM * EDIM;                 // +Wf2
    const int T3 = T2 + 64 * HDIM;                   // +W_atom (padded K=64)
    const int T4 = T3 + N_NODES * 16;                // +xprep (16 ushort4 slots/node)
    const int stride = gridDim.x * 256;
    for (int idx = blockIdx.x * 256 + threadIdx.x; idx < T4; idx += stride) {
        if (idx < 4 * WSZ) {                         // W1: K=256, N=512 -> t1 [512][256]
            const int l = idx >> 17, e = idx & (WSZ - 1);
            const int k = e >> 9, n = e & 511;
            t1[(size_t)l * WSZ + n * HDIM + k] = f2bf(W1[idx]);
        } else if (idx < T0) {                       // W2: K=512, N=256 -> t2 [256][512]
            const int r = idx - 4 * WSZ;
            const int l = r >> 17, e = r & (WSZ - 1);
            const int k = e >> 8, n = e & 255;
            t2[(size_t)l * WSZ + n * EDIM + k] = f2bf(W2[r]);
        } else if (idx < T1) {                       // Wf1 -> tf1 [256][256]
            const int e = idx - T0;
            const int k = e >> 8, n = e & 255;
            tf1[n * HDIM + k] = f2bf(Wf1[e]);
        } else if (idx < T2) {                       // Wf2: K=256, N=512 -> tf2 [512][256]
            const int e = idx - T1;
            const int k = e >> 9, n = e & 511;
            tf2[n * HDIM + k] = f2bf(Wf2[e]);
        } else if (idx < T3) {                       // W_atom: [44][256] -> tat [256][64] pad0
            const int e = idx - T2;                  // e over 64*256, k-major per n
            const int n = e >> 6, k = e & 63;
            tat[n * 64 + k] = (k < F_IN) ? f2bf(Wa[k * HDIM + n]) : (unsigned short)0;
        } else {                                     // xprep: x [N][44] -> xb [N][64] pad0
            const int e = idx - T3;
            const int n = e >> 4, k4 = e & 15;
            ushort4 v = make_ushort4(0, 0, 0, 0);
            if (k4 < F_IN / 4) {
                const float4 xv = *(const float4*)(x + (size_t)n * F_IN + k4 * 4);
                v.x = f2bf(xv.x); v.y = f2bf(xv.y); v.z = f2bf(xv.z); v.w = f2bf(xv.w);
            }
            *(ushort4*)(xb + (size_t)n * 64 + k4 * 4) = v;
        }
    }
}

// ============ FUSED GIN LAYER (r24/r25 verified best): 4 waves / 256 threads ============
// H = relu(relu(zin@W1+b1)@W2+b2), z2 never leaves LDS. sB2 early-issue at t==0 (T14).
// r26 lesson: 8-wave split raises bank conflicts and barrier cost while LDS (74KB ->
// 2 blocks/CU) stays the occupancy cap. Keep 4 waves.
__global__ __launch_bounds__(256, 2)
void fused_layer(const unsigned short* __restrict__ zin, const unsigned short* __restrict__ T1,
                 const unsigned short* __restrict__ T2, const float* __restrict__ b1,
                 const float* __restrict__ b2, unsigned short* __restrict__ H, int M) {
    // stageA 8192 | stageB1 4096 | zbuf 9216 ([128][72]) | stageB2 16384  = 37888 us (74KB)
    // epilogue aliases front 33792 us as [128][264]
    __shared__ __align__(16) unsigned short lds[37888];
    unsigned short* sA  = lds;
    unsigned short* sB1 = lds + 8192;
    unsigned short* zb  = lds + 12288;
    unsigned short* sB2 = lds + 21504;

    const int G = gridDim.x;
    int wg = blockIdx.x;
    {   // bijective XCD remap (m204)
        const int q = G >> 3, r = G & 7;
        const int xx = wg & 7, o = wg >> 3;
        wg = (xx < r ? xx * (q + 1) : r * (q + 1) + (xx - r) * q) + o;
    }
    const int row0 = wg << 7;

    const int tid = threadIdx.x;
    const int lane = tid & 63;
    const int w = tid >> 6;
    const int wr = w >> 1, wc = w & 1;
    const int lr = lane & 15;
    const int l4 = lane >> 4;
    const int rgrp = l4 * 4;
    const int srow = tid >> 3;                              // 0..31
    const int sgran = ((tid & 7) ^ (srow & 7)) << 3;        // pre-swizzled src granule

    floatx4 acc_h[4][8];
#pragma unroll
    for (int m = 0; m < 4; ++m)
#pragma unroll
        for (int n = 0; n < 8; ++n) acc_h[m][n] = (floatx4){0.f, 0.f, 0.f, 0.f};

#pragma unroll 1
    for (int c = 0; c < 8; ++c) {
        floatx4 acc_z[4][2];
#pragma unroll
        for (int m = 0; m < 4; ++m)
#pragma unroll
            for (int n = 0; n < 2; ++n) acc_z[m][n] = (floatx4){0.f, 0.f, 0.f, 0.f};

        // ---- phase A: 4 K-steps over zin K=256 ----
#pragma unroll 1
        for (int t = 0; t < 4; ++t) {
            __syncthreads();             // stage buffers free (t==0: prev sB2 readers too)
#pragma unroll
            for (int p = 0; p < 4; ++p) {                   // zin [128][64]
                const int r = (p << 5) + srow;
                int ar = row0 + r; if (ar >= M) ar = M - 1;
                gload16(zin + (size_t)ar * 256 + (t << 6) + sgran, &sA[(p << 11) + (w << 9)]);
            }
#pragma unroll
            for (int p = 0; p < 2; ++p) {                   // W1 slice rows c*64.. [64][64]
                const int r = (p << 5) + srow;
                gload16(T1 + (size_t)((c << 6) + r) * 256 + (t << 6) + sgran,
                        &sB1[(p << 11) + (w << 9)]);
            }
            if (t == 0) {
                // early-issue W2T k-slice [256][64] for this c (T14): latency hides
                // under the whole of phase A instead of the zbuf-write window.
#pragma unroll
                for (int p = 0; p < 8; ++p) {
                    const int r = (p << 5) + srow;
                    gload16(T2 + (size_t)r * 512 + (c << 6) + sgran,
                            &sB2[(p << 11) + (w << 9)]);
                }
            }
            __syncthreads();             // compiler drains vmcnt before barrier
#pragma unroll
            for (int s = 0; s < 2; ++s) {
                const int pg = (((s << 2) + l4) ^ (lr & 7)) << 3;
                bhalf8 fa[4], fb[2];
#pragma unroll
                for (int m = 0; m < 4; ++m)
                    fa[m] = *(const bhalf8*)&sA[((wr << 6) + (m << 4) + lr) * 64 + pg];
#pragma unroll
                for (int n = 0; n < 2; ++n)
                    fb[n] = *(const bhalf8*)&sB1[((wc << 5) + (n << 4) + lr) * 64 + pg];
#pragma unroll
                for (int m = 0; m < 4; ++m)
#pragma unroll
                    for (int n = 0; n < 2; ++n)
                        acc_z[m][n] = __builtin_amdgcn_mfma_f32_16x16x32_bf16(fa[m], fb[n], acc_z[m][n], 0, 0, 0);
            }
        }

        // ---- z2c -> zbuf (bf16, relu+bias), unswizzled [128][72] ----
#pragma unroll
        for (int n = 0; n < 2; ++n) {
            const int ck = (wc << 5) + (n << 4) + lr;       // 0..63
            const float bv = b1[(c << 6) + ck];
#pragma unroll
            for (int m = 0; m < 4; ++m) {
                const int rw = (wr << 6) + (m << 4) + rgrp;
#pragma unroll
                for (int j = 0; j < 4; ++j)
                    zb[(rw + j) * 72 + ck] = f2bf(fmaxf(acc_z[m][n][j] + bv, 0.f));
            }
        }
        __syncthreads();                 // zbuf visible; sB2 landed long ago

        // ---- phase B: acc_h += zbuf[128][64] @ W2T-slice ----
#pragma unroll
        for (int s = 0; s < 2; ++s) {
            const int pg = (((s << 2) + l4) ^ (lr & 7)) << 3;
            const int zg = ((s << 2) + l4) << 3;            // zbuf granule (no swizzle)
            bhalf8 fa[4], fb[8];
#pragma unroll
            for (int m = 0; m < 4; ++m)
                fa[m] = *(const bhalf8*)&zb[((wr << 6) + (m << 4) + lr) * 72 + zg];
#pragma unroll
            for (int n = 0; n < 8; ++n)
                fb[n] = *(const bhalf8*)&sB2[((wc << 7) + (n << 4) + lr) * 64 + pg];
#pragma unroll
            for (int m = 0; m < 4; ++m)
#pragma unroll
                for (int n = 0; n < 8; ++n)
                    acc_h[m][n] = __builtin_amdgcn_mfma_f32_16x16x32_bf16(fa[m], fb[n], acc_h[m][n], 0, 0, 0);
        }
    }

    // ---- epilogue: relu+bias -> bf16, LDS-staged coalesced write (r12 pattern) ----
    __syncthreads();
#pragma unroll
    for (int n = 0; n < 8; ++n) {
        const int colt = (wc << 7) + (n << 4) + lr;
        const float bv = b2[colt];
#pragma unroll
        for (int m = 0; m < 4; ++m) {
            const int rwt = (wr << 6) + (m << 4) + rgrp;
#pragma unroll
            for (int j = 0; j < 4; ++j)
                lds[(rwt + j) * 264 + colt] = f2bf(fmaxf(acc_h[m][n][j] + bv, 0.f));
        }
    }
    __syncthreads();
    const int orow = tid >> 1;
    const int ohalf = (tid & 1) << 7;    // 128 us = 256B halves
    if (row0 + orow < M) {
        const uint4* sp = (const uint4*)(lds + orow * 264 + ohalf);
        uint4* dp = (uint4*)(H + (size_t)(row0 + orow) * 256 + ohalf);
#pragma unroll
        for (int q = 0; q < 16; ++q) dp[q] = sp[q];
    }
}

// ---------------- MFMA GEMM (r17): counted-vmcnt double-buffer; atom + head only ---------
template <int OUT>
__global__ __launch_bounds__(256)
void gemm_mfma(const unsigned short* __restrict__ A, const unsigned short* __restrict__ BT,
               const float* __restrict__ bias, float* __restrict__ C,
               unsigned short* __restrict__ Z, int M, int N, int KK) {
    __shared__ __align__(16) unsigned short lds_all[32768];   // 64 KB

    const int ncol = N >> 7;
    const int G = gridDim.x;
    int wg = blockIdx.x;
    {   // bijective XCD remap (m204)
        const int q = G >> 3, r = G & 7;
        const int xx = wg & 7, o = wg >> 3;
        wg = (xx < r ? xx * (q + 1) : r * (q + 1) + (xx - r) * q) + o;
    }
    const int col0 = (wg % ncol) << 7;
    const int row0 = (wg / ncol) << 7;

    const int tid = threadIdx.x;
    const int lane = tid & 63;
    const int w = tid >> 6;
    const int wr = w >> 1, wc = w & 1;
    const int lr = lane & 15;
    const int l4 = lane >> 4;
    const int srow = tid >> 3;
    const int sgran = ((tid & 7) ^ (srow & 7)) << 3;

    floatx4 acc[4][4];
#pragma unroll
    for (int m = 0; m < 4; ++m)
#pragma unroll
        for (int n = 0; n < 4; ++n) acc[m][n] = (floatx4){0.f, 0.f, 0.f, 0.f};

    const int NT = KK >> 6;

    auto stage = [&](int t, int b) {
        const int k0 = t << 6;
        unsigned short* la = &lds_all[b * 16384];
        unsigned short* lb = la + 8192;
#pragma unroll
        for (int pass = 0; pass < 4; ++pass) {
            const int r = (pass << 5) + srow;
            int ar = row0 + r; if (ar >= M) ar = M - 1;
            gload16(A + (size_t)ar * KK + k0 + sgran, &la[(pass << 11) + (w << 9)]);
            gload16(BT + (size_t)(col0 + r) * KK + k0 + sgran, &lb[(pass << 11) + (w << 9)]);
        }
    };

    stage(0, 0);
    if (NT > 1) stage(1, 1);
    for (int t = 0; t < NT; ++t) {
        const int cur = t & 1;
        if (t + 1 < NT) {
            asm volatile("s_waitcnt vmcnt(8)" ::: "memory");
        } else {
            asm volatile("s_waitcnt vmcnt(0)" ::: "memory");
        }
        __builtin_amdgcn_s_barrier();

        const unsigned short* la = &lds_all[cur * 16384];
        const unsigned short* lb = la + 8192;
#pragma unroll
        for (int s = 0; s < 2; ++s) {
            const int pg = (((s << 2) + l4) ^ (lr & 7)) << 3;
            bhalf8 fa[4], fb[4];
#pragma unroll
            for (int m = 0; m < 4; ++m)
                fa[m] = *(const bhalf8*)&la[((wr << 6) + (m << 4) + lr) * 64 + pg];
#pragma unroll
            for (int n = 0; n < 4; ++n)
                fb[n] = *(const bhalf8*)&lb[((wc << 6) + (n << 4) + lr) * 64 + pg];
#pragma unroll
            for (int m = 0; m < 4; ++m)
#pragma unroll
                for (int n = 0; n < 4; ++n)
                    acc[m][n] = __builtin_amdgcn_mfma_f32_16x16x32_bf16(fa[m], fb[n], acc[m][n], 0, 0, 0);
        }

        __builtin_amdgcn_s_barrier();
        if (t + 2 < NT) stage(t + 2, cur);
    }

    const int rgrp = l4 * 4;
    if (OUT == 2) {
        __syncthreads();
#pragma unroll
        for (int n = 0; n < 4; ++n) {
            const int colt = (wc << 6) + (n << 4) + lr;
            const float bv = bias[col0 + colt];
#pragma unroll
            for (int m = 0; m < 4; ++m) {
                const int rwt = (wr << 6) + (m << 4) + rgrp;
#pragma unroll
                for (int j = 0; j < 4; ++j)
                    lds_all[(rwt + j) * 136 + colt] = f2bf(fmaxf(acc[m][n][j] + bv, 0.f));
            }
        }
        __syncthreads();
        const int orow = tid >> 1;
        const int ocol = (tid & 1) << 6;
        if (row0 + orow < M) {
            const uint4* sp = (const uint4*)(lds_all + orow * 136 + ocol);
            uint4* dp = (uint4*)(Z + (size_t)(row0 + orow) * N + col0 + ocol);
#pragma unroll
            for (int q = 0; q < 8; ++q) dp[q] = sp[q];
        }
    } else {
#pragma unroll
        for (int n = 0; n < 4; ++n) {
            const int col = col0 + (wc << 6) + (n << 4) + lr;
            const float bv = bias[col];
#pragma unroll
            for (int m = 0; m < 4; ++m) {
                const int rw = row0 + (wr << 6) + (m << 4) + rgrp;
#pragma unroll
                for (int j = 0; j < 4; ++j) {
                    const int row = rw + j;
                    if (row < M) C[(size_t)row * N + col] = acc[m][n][j] + bv;
                }
            }
        }
    }
}

// ------- pool: sorted-batch segment mean over bf16 h -> bf16 [g][HDIM] -------
__global__ void pool_kernel(const unsigned short* __restrict__ h,
                            const int* __restrict__ batch,
                            unsigned short* __restrict__ gz) {
    __shared__ int sse[2];
    const int g = blockIdx.x;
    if (threadIdx.x < 2) {
        const int target = g + threadIdx.x;
        int lo = 0, hi = N_NODES;
        while (lo < hi) {
            const int mid = (lo + hi) >> 1;
            if (batch[mid] < target) lo = mid + 1; else hi = mid;
        }
        sse[threadIdx.x] = lo;
    }
    __syncthreads();
    const int s = sse[0], e = sse[1];
    const int j = threadIdx.x;
    float acc = 0.f;
    for (int n = s; n < e; ++n) acc += bf2f(h[(size_t)n * HDIM + j]);
    const float v = acc * ((e > s) ? 1.f / (float)(e - s) : 1.f);
    gz[(size_t)g * HDIM + j] = f2bf(v);
}

extern "C" void kernel_launch(void* const* d_in, const int* in_sizes, int n_in,
                              void* d_out, int out_size, void* d_ws, size_t ws_size,
                              hipStream_t stream) {
    const float* x      = (const float*)d_in[0];
    const int*   eidx   = (const int*)d_in[1];
    const int*   batch  = (const int*)d_in[2];
    const float* W_atom = (const float*)d_in[3];
    const float* b_atom = (const float*)d_in[4];
    const float* W1     = (const float*)d_in[5];
    const float* b1     = (const float*)d_in[6];
    const float* W2     = (const float*)d_in[7];
    const float* b2     = (const float*)d_in[8];
    const float* Wf1    = (const float*)d_in[9];
    const float* bf1    = (const float*)d_in[10];
    const float* Wf2    = (const float*)d_in[11];
    const float* bf2    = (const float*)d_in[12];
    float* out = (float*)d_out;

    const int* src = eidx;
    const int* dst = eidx + N_EDGES;

    const size_t NH = (size_t)N_NODES * HDIM;           // 25.6M elems
    const int WSZ = HDIM * 2 * HDIM;                    // 131072 elems per layer weight

    // ---- workspace layout ----
    char* base = (char*)d_ws;
    size_t off = 0;
    unsigned short* h = (unsigned short*)(base + off);      off += NH * 2;  // bf16 [N][256]
    unsigned short* zin = (unsigned short*)(base + off);    off += NH * 2;  // bf16 [N][256]
    unsigned short* xb = (unsigned short*)(base + off);     off += (size_t)N_NODES * 64 * 2;
    int* deg     = (int*)(base + off);            off += (size_t)N_NODES * 4;
    int* row_ptr = (int*)(base + off);            off += (size_t)(N_NODES + 1) * 4;
    int* cursor  = (int*)(base + off);            off += (size_t)N_NODES * 4;
    int* eids    = (int*)(base + off);            off += (size_t)N_EDGES * 4;
    int* blk     = (int*)(base + off);            off += 512 * 4;
    off = (off + 255) & ~(size_t)255;
    unsigned short* t1 = (unsigned short*)(base + off); off += (size_t)NLAYERS * WSZ * 2;
    unsigned short* t2 = (unsigned short*)(base + off); off += (size_t)NLAYERS * WSZ * 2;
    unsigned short* tf1 = (unsigned short*)(base + off); off += (size_t)HDIM * HDIM * 2;
    unsigned short* tf2 = (unsigned short*)(base + off); off += (size_t)HDIM * EDIM * 2;
    unsigned short* tat = (unsigned short*)(base + off); off += (size_t)HDIM * 64 * 2;
    off = (off + 255) & ~(size_t)255;

    // head buffers overlap the (dead-after-layers) zin region
    const size_t GH = (size_t)N_GRAPHS * HDIM;
    unsigned short* hg  = zin;            // [4000][256] bf16
    unsigned short* hg1 = zin + GH;       // [4000][256] bf16

    const int nb = (N_NODES + 255) / 256;
    const int nrow128 = (N_NODES + 127) / 128;   // 782

    // 1. fused prep: weights -> transposed bf16 AND x -> xb (one dispatch)
    wprep_all<<<1024, 256, 0, stream>>>(W1, W2, Wf1, Wf2, W_atom, x,
                                        t1, t2, tf1, tf2, tat, xb);

    // 2. CSR build (+ deterministic segment sort; cursor folded into scan3)
    zero_kernel<<<128, 256, 0, stream>>>((float*)deg, N_NODES / 4);
    hist_kernel<<<(N_EDGES + 255) / 256, 256, 0, stream>>>(dst, deg);
    scan1_kernel<<<nb, 256, 0, stream>>>(deg, row_ptr, blk);
    scan2_kernel<<<1, 64, 0, stream>>>(blk, nb);
    scan3_kernel<<<nb, 256, 0, stream>>>(row_ptr, blk, cursor);
    fill_kernel<<<(N_EDGES + 255) / 256, 256, 0, stream>>>(src, dst, cursor, eids);
    sort_kernel<<<nb, 256, 0, stream>>>(row_ptr, eids);   // deterministic gather order

    // 3. atom MLP as MFMA GEMM: h = relu(xb @ W_atom + b_atom)  [100000, 256], KK=64
    gemm_mfma<2><<<2 * nrow128, 256, 0, stream>>>(
        xb, tat, b_atom, nullptr, h, N_NODES, HDIM, 64);

    // 4. GIN layers: gather (8 nodes/block, 2-way unrolled) + fused kernel per layer
    for (int l = 0; l < NLAYERS; ++l) {
        gather_kernel<<<N_NODES / 8, 256, 0, stream>>>(h, row_ptr, eids, zin);
        fused_layer<<<nrow128, 256, 0, stream>>>(
            zin, t1 + (size_t)l * WSZ, t2 + (size_t)l * WSZ,
            b1 + (size_t)l * 2 * HDIM, b2 + (size_t)l * HDIM, h, N_NODES);
    }

    // 5. pool (bf16 in/out)
    pool_kernel<<<N_GRAPHS, HDIM, 0, stream>>>(h, batch, hg);

    // 6. head
    gemm_mfma<2><<<2 * ((N_GRAPHS + 127) / 128), 256, 0, stream>>>(
        hg, tf1, bf1, nullptr, hg1, N_GRAPHS, HDIM, HDIM);
    gemm_mfma<0><<<4 * ((N_GRAPHS + 127) / 128), 256, 0, stream>>>(
        hg1, tf2, bf2, out, nullptr, N_GRAPHS, EDIM, HDIM);
}